// Round 6
// baseline (1682.339 us; speedup 1.0000x reference)
//
#include <hip/hip_runtime.h>
#include <hip/hip_cooperative_groups.h>

namespace cg = cooperative_groups;

// ConvLSTM2D via MFMA implicit-GEMM. B=8,T=16,H=W=64,Cin=32,F=64,3x3 SAME.
// Round 13: PERSISTENT cooperative kernel. R7-R12: five different K-loop
// schedules/occupancies all land 428-464us -> the schedule isn't the
// bottleneck; the invariant costs are the 17-launch structure (gaps,
// blocks hopping CUs each step), per-step c read+write through global,
// and per-step re-staging of the full h halo. Fuse all 16 steps into one
// cooperative kernel, 256 blocks (=1/CU at 135KB LDS) x 512 thr:
//   - c lives in 16 VGPRs/thread for the whole sequence (never in memory)
//   - epilogue writes own-tile h straight into hs_s; only the 52-px halo
//     ring is staged from a global bf16 ping-pong per step
//   - inter-step sync = __threadfence + grid.sync() (device-scope release
//     of h for cross-XCD neighbor reads)
// K-loop body = R11's group-of-3 (best measured): shared P=6 ring (96KB),
// one __syncthreads per 3 k-steps (its vmcnt(0) drain certifies the DMAed
// slots), everything compile-time via unrolled macro groups.

#define TSTEPS 16

typedef short bf16x8 __attribute__((ext_vector_type(8)));
typedef float f32x4 __attribute__((ext_vector_type(4)));
typedef unsigned int __attribute__((address_space(1))) gu32;
typedef unsigned int __attribute__((address_space(3))) lu32;

__device__ __forceinline__ float hsig(float x) {
    return fminf(fmaxf((x + 3.0f) * (1.0f / 6.0f), 0.0f), 1.0f);
}

__device__ __forceinline__ unsigned short f2bf(float f) {
    union { float f; unsigned int u; } v; v.f = f;
    unsigned int r = v.u + 0x7fffu + ((v.u >> 16) & 1u);  // RNE
    return (unsigned short)(r >> 16);
}

// ---- weight prepack: Wg(3,3,32,256), Ug(3,3,64,256) fp32 -> bf16 B-frags ----
// layout out[s(27)][nt(16)][lane(64)][8]: per (s,nt) one contiguous 1 KB line.
__global__ __launch_bounds__(256)
void prepack_w(const float* __restrict__ Wg, const float* __restrict__ Ug,
               unsigned short* __restrict__ out)
{
    int idx = blockIdx.x * 256 + threadIdx.x;   // 27*16*64 = 27648
    if (idx >= 27648) return;
    int lane = idx & 63;
    int nt   = (idx >> 6) & 15;
    int s    = idx >> 10;
    int col = lane & 15, quad = lane >> 4;
    int n = nt * 16 + col;
    int k0 = quad * 8;
    const float* src;
    if (s < 9) {
        src = Wg + ((size_t)s * 32 + k0) * 256 + n;
    } else {
        int ss = s - 9; int tap = ss >> 1; int half = ss & 1;
        src = Ug + ((size_t)tap * 64 + half * 32 + k0) * 256 + n;
    }
    unsigned short tmp[8];
    #pragma unroll
    for (int j = 0; j < 8; ++j) tmp[j] = f2bf(src[(size_t)j * 256]);
    *(uint4*)(out + (size_t)idx * 8) = *(uint4*)tmp;
}

// ---- the whole ConvLSTM sequence in one cooperative kernel ----
__global__ __launch_bounds__(512)
__attribute__((amdgpu_waves_per_eu(2, 2)))
void convlstm_all(const float* __restrict__ x,        // (B,T,64,64,32) fp32
                  const unsigned short* __restrict__ wpk,
                  const float* __restrict__ bias,     // (256)
                  float* __restrict__ c_st,           // fp32 (B,64,64,64) = d_out (final h)
                  unsigned short* __restrict__ hA,    // bf16 ping (B,64,64,64)
                  unsigned short* __restrict__ hB)    // bf16 pong
{
    constexpr int P = 6;   // B ring depth (2 groups of 3 k-steps)

    // tile: 16 rows (y) x 8 cols (x) = 128 px; halo 18x10 = 180 px
    __shared__ __align__(16) unsigned short xs_s[180 * 40];   // 14.4 KB
    __shared__ __align__(16) unsigned short hs_s[180 * 72];   // 25.9 KB
    __shared__ __align__(16) unsigned short bring[P * 16 * 512]; // 96.0 KB

    cg::grid_group grid = cg::this_grid();

    const int tid = threadIdx.x;
    const int gx0 = blockIdx.x * 8;
    const int gy0 = blockIdx.y * 16;
    const int b   = blockIdx.z;

    const int lane  = tid & 63;
    const int w     = tid >> 6;        // wave 0..7
    const int pxgrp = w >> 2;          // 0: rows 0-7, 1: rows 8-15
    const int ngrp  = w & 3;           // n-group: nt in {ngrp, ngrp+4, ngrp+8, ngrp+12}
    const int quad  = lane >> 4;
    const int m     = lane & 15;
    const int ch    = ngrp * 16 + m;   // output channel 0..63

    // ---- B DMA: wave w stages nt {w, w+8} for k-step s into slot s%P ----
    auto issueDMA = [&](int s) {
        int slot = s % P;
        #pragma unroll
        for (int g = 0; g < 2; ++g) {
            int nt = w + 8 * g;
            const unsigned short* gp = wpk + ((size_t)(s * 16 + nt) * 64 + lane) * 8;
            unsigned short* lp = bring + ((size_t)slot * 16 + nt) * 512;  // uniform
            __builtin_amdgcn_global_load_lds((const gu32*)gp, (lu32*)lp, 16, 0, 0);
        }
    };

    // per-thread constant maps
    int xb[4], hb_[4];
    #pragma unroll
    for (int mt = 0; mt < 4; ++mt) {
        int p = mt * 16 + m;
        int row = pxgrp * 8 + (p >> 3);
        int cc  = p & 7;
        xb[mt]  = (row * 10 + cc) * 40 + quad * 8;
        hb_[mt] = (row * 10 + cc) * 72 + quad * 8;
    }
    float bv[4];
    #pragma unroll
    for (int g = 0; g < 4; ++g) bv[g] = bias[g * 64 + ch];

    // c state: 16 fp32 per thread, lives here for all 16 steps
    float creg[4][4];
    #pragma unroll
    for (int mt = 0; mt < 4; ++mt)
        #pragma unroll
        for (int r = 0; r < 4; ++r) creg[mt][r] = 0.0f;

    const unsigned short* hin = hA;
    unsigned short*       hout = hB;

    // one k-group: optionally issue the next group's 3 DMA slots, then 3
    // fully-unrolled k-steps (compile-time s), then a barrier whose
    // vmcnt(0)+lgkmcnt(0) drain certifies the DMAed slots for all waves.
#define KGROUP(G0, DOISSUE)                                                      \
    {                                                                            \
        if (DOISSUE) { issueDMA((G0) + 3); issueDMA((G0) + 4); issueDMA((G0) + 5); } \
        _Pragma("unroll")                                                        \
        for (int j = 0; j < 3; ++j) {                                            \
            const int s = (G0) + j;                                              \
            const int slot = s % P;                                              \
            bf16x8 bfr[4];                                                       \
            _Pragma("unroll")                                                    \
            for (int g = 0; g < 4; ++g)                                          \
                bfr[g] = *(const bf16x8*)(bring + ((size_t)slot * 16 + (ngrp + 4 * g)) * 512 + lane * 8); \
            bf16x8 a[4];                                                         \
            if (s < 9) {                                                         \
                int taplin = (s / 3) * 10 + (s % 3);                             \
                _Pragma("unroll")                                                \
                for (int mt = 0; mt < 4; ++mt)                                   \
                    a[mt] = *(const bf16x8*)(xs_s + xb[mt] + taplin * 40);       \
            } else {                                                             \
                int ss = s - 9, tap = ss >> 1, half = ss & 1;                    \
                int taplin = (tap / 3) * 10 + (tap % 3);                         \
                _Pragma("unroll")                                                \
                for (int mt = 0; mt < 4; ++mt)                                   \
                    a[mt] = *(const bf16x8*)(hs_s + hb_[mt] + taplin * 72 + half * 32); \
            }                                                                    \
            _Pragma("unroll")                                                    \
            for (int g = 0; g < 4; ++g) {                                        \
                _Pragma("unroll")                                                \
                for (int mt = 0; mt < 4; ++mt)                                   \
                    acc[mt][g] = __builtin_amdgcn_mfma_f32_16x16x32_bf16(a[mt], bfr[g], acc[mt][g], 0, 0, 0); \
            }                                                                    \
        }                                                                        \
        __syncthreads();                                                         \
    }

    #pragma unroll 1
    for (int t = 0; t < TSTEPS; ++t) {
        const bool hp = (t > 0);

        // prologue DMAs for slots 0-2; certified by the staging barrier
        issueDMA(0); issueDMA(1); issueDMA(2);

        // ---- stage x(t) halo (fp32 -> bf16), 180 px ----
        {
            const float* xt = x + (((size_t)b * TSTEPS + t) * (size_t)(64 * 64 * 32));
            #pragma unroll 3
            for (int idx = tid; idx < 180 * 8; idx += 512) {
                int pix = idx >> 3, q = idx & 7;
                int iy = pix / 10, ix = pix - iy * 10;
                int gy = gy0 + iy - 1, gx = gx0 + ix - 1;
                unsigned short o[4] = {0, 0, 0, 0};
                if ((unsigned)gy < 64u && (unsigned)gx < 64u) {
                    float4 v = *(const float4*)(xt + ((size_t)(gy * 64 + gx) * 32) + q * 4);
                    o[0] = f2bf(v.x); o[1] = f2bf(v.y); o[2] = f2bf(v.z); o[3] = f2bf(v.w);
                }
                *(ushort4*)(xs_s + pix * 40 + q * 4) = *(ushort4*)o;
            }
        }
        // ---- stage h halo BORDER only (52 px); own 128 px already in hs_s ----
        if (hp) {
            const unsigned short* hb = hin + ((size_t)b * (64 * 64 * 64));
            for (int idx = tid; idx < 52 * 8; idx += 512) {
                int pi = idx >> 3, q = idx & 7;
                int iy, ix;
                if (pi < 10)      { iy = 0;  ix = pi; }
                else if (pi < 20) { iy = 17; ix = pi - 10; }
                else { int j = pi - 20; iy = 1 + (j >> 1); ix = (j & 1) * 9; }
                int gy = gy0 + iy - 1, gx = gx0 + ix - 1;
                uint4 v = make_uint4(0u, 0u, 0u, 0u);
                if ((unsigned)gy < 64u && (unsigned)gx < 64u)
                    v = *(const uint4*)(hb + ((size_t)(gy * 64 + gx) * 64) + q * 8);
                *(uint4*)(hs_s + (iy * 10 + ix) * 72 + q * 8) = v;
            }
        }
        __syncthreads();   // staging + ring slots 0-2 visible (full vmcnt drain)

        // acc init = bias
        f32x4 acc[4][4];   // [mt][gate]
        #pragma unroll
        for (int g = 0; g < 4; ++g) {
            f32x4 bi = (f32x4){bv[g], bv[g], bv[g], bv[g]};
            #pragma unroll
            for (int mt = 0; mt < 4; ++mt) acc[mt][g] = bi;
        }

        // ---- K-loop: groups of 3 k-steps between barriers ----
        KGROUP(0, true);
        KGROUP(3, true);
        KGROUP(6, hp);
        if (hp) {
            KGROUP(9,  true);
            KGROUP(12, true);
            KGROUP(15, true);
            KGROUP(18, true);
            KGROUP(21, true);
            KGROUP(24, false);
        }

        // ---- epilogue: gates + in-register state update ----
        // C/D layout: col = lane&15 (channel), row = quad*4 + r (pixel)
        const int last = (t == TSTEPS - 1);
        #pragma unroll
        for (int mt = 0; mt < 4; ++mt) {
            #pragma unroll
            for (int r = 0; r < 4; ++r) {
                int p = mt * 16 + quad * 4 + r;
                int py = pxgrp * 8 + (p >> 3), px = p & 7;
                size_t gidx = (((size_t)b * 64 + (gy0 + py)) * 64 + (gx0 + px)) * 64 + ch;
                float zi = acc[mt][0][r];
                float zf = acc[mt][1][r];
                float zc = acc[mt][2][r];
                float zo = acc[mt][3][r];
                float cn = hsig(zf) * creg[mt][r] + hsig(zi) * fmaxf(zc, 0.0f);
                float hn = hsig(zo) * fmaxf(cn, 0.0f);
                creg[mt][r] = cn;
                if (last) {
                    c_st[gidx] = hn;                 // d_out gets final h (fp32)
                } else {
                    unsigned short hv = f2bf(hn);
                    hout[gidx] = hv;                 // neighbors read next step
                    hs_s[((py + 1) * 10 + (px + 1)) * 72 + ch] = hv;  // own tile stays local
                }
            }
        }

        if (!last) {
            __threadfence();   // release h writes device-wide (cross-XCD)
            grid.sync();       // all blocks' h(t+1) published
            const unsigned short* tmp = hin;
            hin = hout; hout = (unsigned short*)tmp;
        }
    }
#undef KGROUP
}

extern "C" void kernel_launch(void* const* d_in, const int* in_sizes, int n_in,
                              void* d_out, int out_size, void* d_ws, size_t ws_size,
                              hipStream_t stream) {
    const float* x  = (const float*)d_in[0];
    const float* Wg = (const float*)d_in[1];
    const float* Ug = (const float*)d_in[2];
    const float* bs = (const float*)d_in[3];

    // ws layout: [packed weights 442368 B][h0 bf16 4 MB][h1 bf16 4 MB]
    unsigned short* wpk = (unsigned short*)d_ws;
    unsigned short* h0  = (unsigned short*)((char*)d_ws + 27 * 16 * 64 * 8 * 2);
    unsigned short* h1  = h0 + (size_t)8 * 64 * 64 * 64;
    float* cS = (float*)d_out;

    prepack_w<<<108, 256, 0, stream>>>(Wg, Ug, wpk);

    dim3 grid(8, 4, 8);   // 256 blocks = 1 per CU (135 KB LDS)
    dim3 block(512);
    void* args[] = { (void*)&x, (void*)&wpk, (void*)&bs,
                     (void*)&cS, (void*)&h0, (void*)&h1 };
    hipLaunchCooperativeKernel((const void*)convlstm_all, grid, block, args, 0, stream);
}

// Round 7
// 373.119 us; speedup vs baseline: 4.5088x; 4.5088x over previous
//
#include <hip/hip_runtime.h>

// ConvLSTM2D via MFMA implicit-GEMM. B=8,T=16,H=W=64,Cin=32,F=64,3x3 SAME.
// Round 14: R11 skeleton (group-of-3 K-loop, best measured family) + two
// T14-style async latency splits on the serial chains OUTSIDE the K-loop:
//  (1) h-halo staging: ISSUE the 3 uint4 global loads per thread into regs
//      BEFORE the x-staging work, ds_write them after -- the ~900cy HBM
//      chain (h written by other CUs/XCDs last launch) hides under the
//      x-stage instead of serializing after it.
//  (2) epilogue c-read: prefetch c_st into cpre[4][4] regs at k-group 18
//      (~8K cyc before use); completion piggybacks on existing group
//      barrier vmcnt drains, so the epilogue reads registers instead of
//      stalling ~900cy on 16 scattered loads.
// Context: R7-R12 = five K-loop schedules/occupancies, all 428-464us with
// nothing saturated; R13 persistent+grid.sync = 1682us (device-scope
// fences kill XCD L2 reuse; counters finally visible: MfmaUtil 5.6%,
// VALUBusy 2.7% -> latency-bound, not pipe-bound). So: attack the
// remaining serial latency chains, keep the proven 17-launch structure.

#define TSTEPS 16

typedef short bf16x8 __attribute__((ext_vector_type(8)));
typedef float f32x4 __attribute__((ext_vector_type(4)));
typedef unsigned int __attribute__((address_space(1))) gu32;
typedef unsigned int __attribute__((address_space(3))) lu32;

__device__ __forceinline__ float hsig(float x) {
    return fminf(fmaxf((x + 3.0f) * (1.0f / 6.0f), 0.0f), 1.0f);
}

__device__ __forceinline__ unsigned short f2bf(float f) {
    union { float f; unsigned int u; } v; v.f = f;
    unsigned int r = v.u + 0x7fffu + ((v.u >> 16) & 1u);  // RNE
    return (unsigned short)(r >> 16);
}

// ---- weight prepack: Wg(3,3,32,256), Ug(3,3,64,256) fp32 -> bf16 B-frags ----
// layout out[s(27)][nt(16)][lane(64)][8]: per (s,nt) one contiguous 1 KB line.
__global__ __launch_bounds__(256)
void prepack_w(const float* __restrict__ Wg, const float* __restrict__ Ug,
               unsigned short* __restrict__ out)
{
    int idx = blockIdx.x * 256 + threadIdx.x;   // 27*16*64 = 27648
    if (idx >= 27648) return;
    int lane = idx & 63;
    int nt   = (idx >> 6) & 15;
    int s    = idx >> 10;
    int col = lane & 15, quad = lane >> 4;
    int n = nt * 16 + col;
    int k0 = quad * 8;
    const float* src;
    if (s < 9) {
        src = Wg + ((size_t)s * 32 + k0) * 256 + n;
    } else {
        int ss = s - 9; int tap = ss >> 1; int half = ss & 1;
        src = Ug + ((size_t)tap * 64 + half * 32 + k0) * 256 + n;
    }
    unsigned short tmp[8];
    #pragma unroll
    for (int j = 0; j < 8; ++j) tmp[j] = f2bf(src[(size_t)j * 256]);
    *(uint4*)(out + (size_t)idx * 8) = *(uint4*)tmp;
}

// ---- one ConvLSTM step (NS = 9 for t==0, 27 otherwise) ----
template<int NS>
__global__ __launch_bounds__(512)
__attribute__((amdgpu_waves_per_eu(2, 2)))
void convlstm_step(const float* __restrict__ x,       // (B,T,64,64,32) fp32
                   const unsigned short* __restrict__ wpk,
                   const float* __restrict__ bias,    // (256)
                   const unsigned short* __restrict__ h_in, // bf16 (B,64,64,64)
                   float* __restrict__ c_st,          // fp32 (B,64,64,64) = d_out
                   unsigned short* __restrict__ h_out,// bf16 ping
                   int t, int is_last)
{
    constexpr bool HP = (NS == 27);
    constexpr int  P  = 6;   // B ring depth (2 groups of 3 k-steps)

    // tile: 16 rows (y) x 8 cols (x) = 128 px; halo 18x10 = 180 px
    __shared__ __align__(16) unsigned short xs_s[180 * 40];           // 14.4 KB
    __shared__ __align__(16) unsigned short hs_s[HP ? 180 * 72 : 8];  // 25.9 KB
    __shared__ __align__(16) unsigned short bring[P * 16 * 512];      // 96.0 KB

    const int tid = threadIdx.x;
    const int gx0 = blockIdx.x * 8;
    const int gy0 = blockIdx.y * 16;
    const int b   = blockIdx.z;

    const int lane  = tid & 63;
    const int w     = tid >> 6;        // wave 0..7
    const int pxgrp = w >> 2;          // 0: rows 0-7, 1: rows 8-15
    const int ngrp  = w & 3;           // n-group: nt in {ngrp, ngrp+4, ngrp+8, ngrp+12}
    const int quad  = lane >> 4;
    const int m     = lane & 15;
    const int ch    = ngrp * 16 + m;   // output channel 0..63

    // ---- B DMA: wave w stages nt {w, w+8} for k-step s into slot s%P ----
    auto issueDMA = [&](int s) {
        int slot = s % P;
        #pragma unroll
        for (int g = 0; g < 2; ++g) {
            int nt = w + 8 * g;
            const unsigned short* gp = wpk + ((size_t)(s * 16 + nt) * 64 + lane) * 8;
            unsigned short* lp = bring + ((size_t)slot * 16 + nt) * 512;  // uniform
            __builtin_amdgcn_global_load_lds((const gu32*)gp, (lu32*)lp, 16, 0, 0);
        }
    };

    // ---- prologue: fill group-0 slots; staging barrier certifies them ----
    issueDMA(0);
    issueDMA(1);
    issueDMA(2);

    // ---- (1) h halo: ISSUE loads into regs first (latency hides under
    // the x-staging work below). 1440 items / 512 thr = 3 rounds (3rd
    // partial: tid < 416).
    uint4 hv0 = make_uint4(0u,0u,0u,0u), hv1 = make_uint4(0u,0u,0u,0u),
          hv2 = make_uint4(0u,0u,0u,0u);
    int ho0 = 0, ho1 = 0, ho2 = -1;
    if constexpr (HP) {
        const unsigned short* hb = h_in + ((size_t)b * (64 * 64 * 64));
        auto issueH = [&](int idx, uint4& v, int& off) {
            int pix = idx >> 3, q = idx & 7;
            int iy = pix / 10, ix = pix - iy * 10;
            int gy = gy0 + iy - 1, gx = gx0 + ix - 1;
            if ((unsigned)gy < 64u && (unsigned)gx < 64u)
                v = *(const uint4*)(hb + ((size_t)(gy * 64 + gx) * 64) + q * 8);
            off = pix * 72 + q * 8;
        };
        issueH(tid,        hv0, ho0);
        issueH(tid + 512,  hv1, ho1);
        if (tid < 416) issueH(tid + 1024, hv2, ho2);
    }

    // ---- stage x halo (fp32 -> bf16); h loads in flight meanwhile ----
    {
        const float* xt = x + (((size_t)b * TSTEPS + t) * (size_t)(64 * 64 * 32));
        #pragma unroll 3
        for (int idx = tid; idx < 180 * 8; idx += 512) {
            int pix = idx >> 3, q = idx & 7;
            int iy = pix / 10, ix = pix - iy * 10;
            int gy = gy0 + iy - 1, gx = gx0 + ix - 1;
            unsigned short o[4] = {0, 0, 0, 0};
            if ((unsigned)gy < 64u && (unsigned)gx < 64u) {
                float4 v = *(const float4*)(xt + ((size_t)(gy * 64 + gx) * 32) + q * 4);
                o[0] = f2bf(v.x); o[1] = f2bf(v.y); o[2] = f2bf(v.z); o[3] = f2bf(v.w);
            }
            *(ushort4*)(xs_s + pix * 40 + q * 4) = *(ushort4*)o;
        }
    }
    // ---- write h halo to LDS (waits the in-flight loads) ----
    if constexpr (HP) {
        *(uint4*)(hs_s + ho0) = hv0;
        *(uint4*)(hs_s + ho1) = hv1;
        if (ho2 >= 0) *(uint4*)(hs_s + ho2) = hv2;
    }
    __syncthreads();   // staging + ring slots 0-2 visible (full vmcnt drain)

    int xb[4], hb_[4];
    #pragma unroll
    for (int mt = 0; mt < 4; ++mt) {
        int p = mt * 16 + m;
        int row = pxgrp * 8 + (p >> 3);
        int cc  = p & 7;
        xb[mt]  = (row * 10 + cc) * 40 + quad * 8;
        hb_[mt] = (row * 10 + cc) * 72 + quad * 8;
    }

    // acc init = bias
    f32x4 acc[4][4];   // [mt][gate]
    #pragma unroll
    for (int g = 0; g < 4; ++g) {
        float bv = bias[g * 64 + ch];
        f32x4 bi = (f32x4){bv, bv, bv, bv};
        #pragma unroll
        for (int mt = 0; mt < 4; ++mt) acc[mt][g] = bi;
    }

    // (2) c prefetch target; for NS=9 it's just zeros.
    float cpre[4][4];
    if constexpr (!HP) {
        #pragma unroll
        for (int mt = 0; mt < 4; ++mt)
            #pragma unroll
            for (int r = 0; r < 4; ++r) cpre[mt][r] = 0.0f;
    }

    // ---- K-loop: 3 k-steps per barrier, free scheduling within a group ----
    #pragma unroll
    for (int g0 = 0; g0 < NS; g0 += 3) {
        // stage next group's slots (other ring half; consumed-and-published
        // two barriers ago, so overwrite is safe)
        if (g0 + 3 < NS) { issueDMA(g0 + 3); issueDMA(g0 + 4); issueDMA(g0 + 5); }

        // (2) issue the c_st prefetch at group 18: ~8K cyc before the
        // epilogue consumes it; the following group barriers' vmcnt drains
        // absorb its completion.
        if constexpr (HP) {
            if (g0 == 18) {
                #pragma unroll
                for (int mt = 0; mt < 4; ++mt)
                    #pragma unroll
                    for (int r = 0; r < 4; ++r) {
                        int p = mt * 16 + quad * 4 + r;
                        int py = pxgrp * 8 + (p >> 3), px = p & 7;
                        size_t gidx = (((size_t)b * 64 + (gy0 + py)) * 64 + (gx0 + px)) * 64 + ch;
                        cpre[mt][r] = c_st[gidx];
                    }
            }
        }

        #pragma unroll
        for (int j = 0; j < 3; ++j) {
            const int s = g0 + j;           // compile-time
            const int slot = s % P;

            bf16x8 bfr[4];
            #pragma unroll
            for (int g = 0; g < 4; ++g)
                bfr[g] = *(const bf16x8*)(bring + ((size_t)slot * 16 + (ngrp + 4 * g)) * 512 + lane * 8);

            bf16x8 a[4];
            if (s < 9) {
                int taplin = (s / 3) * 10 + (s % 3);
                #pragma unroll
                for (int mt = 0; mt < 4; ++mt)
                    a[mt] = *(const bf16x8*)(xs_s + xb[mt] + taplin * 40);
            } else {
                int ss = s - 9, tap = ss >> 1, half = ss & 1;
                int taplin = (tap / 3) * 10 + (tap % 3);
                #pragma unroll
                for (int mt = 0; mt < 4; ++mt)
                    a[mt] = *(const bf16x8*)(hs_s + hb_[mt] + taplin * 72 + half * 32);
            }

            #pragma unroll
            for (int g = 0; g < 4; ++g)
                #pragma unroll
                for (int mt = 0; mt < 4; ++mt)
                    acc[mt][g] = __builtin_amdgcn_mfma_f32_16x16x32_bf16(a[mt], bfr[g], acc[mt][g], 0, 0, 0);
        }

        // group boundary: drains the in-flight DMAs (vmcnt(0)) and
        // publishes next group's slots to all waves
        __syncthreads();
    }

    // ---- epilogue: gates + state update (c from registers) ----
    // C/D layout: col = lane&15 (channel), row = quad*4 + r (pixel)
    #pragma unroll
    for (int mt = 0; mt < 4; ++mt) {
        #pragma unroll
        for (int r = 0; r < 4; ++r) {
            int p = mt * 16 + quad * 4 + r;
            int py = pxgrp * 8 + (p >> 3), px = p & 7;
            size_t gidx = (((size_t)b * 64 + (gy0 + py)) * 64 + (gx0 + px)) * 64 + ch;
            float zi = acc[mt][0][r];
            float zf = acc[mt][1][r];
            float zc = acc[mt][2][r];
            float zo = acc[mt][3][r];
            float cn = hsig(zf) * cpre[mt][r] + hsig(zi) * fmaxf(zc, 0.0f);
            float hn = hsig(zo) * fmaxf(cn, 0.0f);
            if (is_last) {
                c_st[gidx] = hn;            // d_out gets final h (fp32)
            } else {
                c_st[gidx] = cn;
                h_out[gidx] = f2bf(hn);
            }
        }
    }
}

extern "C" void kernel_launch(void* const* d_in, const int* in_sizes, int n_in,
                              void* d_out, int out_size, void* d_ws, size_t ws_size,
                              hipStream_t stream) {
    const float* x  = (const float*)d_in[0];
    const float* Wg = (const float*)d_in[1];
    const float* Ug = (const float*)d_in[2];
    const float* bs = (const float*)d_in[3];

    // ws layout: [packed weights 442368 B][h0 bf16 4 MB][h1 bf16 4 MB]
    unsigned short* wpk = (unsigned short*)d_ws;
    unsigned short* h0  = (unsigned short*)((char*)d_ws + 27 * 16 * 64 * 8 * 2);
    unsigned short* h1  = h0 + (size_t)8 * 64 * 64 * 64;
    float* cS = (float*)d_out;

    prepack_w<<<108, 256, 0, stream>>>(Wg, Ug, wpk);

    dim3 grid(8, 4, 8);   // 8 x-tiles, 4 y-tiles (16 rows each), 8 batches
    dim3 block(512);
    for (int t = 0; t < TSTEPS; ++t) {
        const unsigned short* hin = (t == 0) ? h0 : ((t & 1) ? h0 : h1);
        unsigned short* hout = (t & 1) ? h1 : h0;
        if (t == 0) {
            convlstm_step<9><<<grid, block, 0, stream>>>(x, wpk, bs, hin, cS, hout, t, 0);
        } else {
            convlstm_step<27><<<grid, block, 0, stream>>>(x, wpk, bs, hin, cS, hout,
                                                          t, (t == TSTEPS - 1) ? 1 : 0);
        }
    }
}

// Round 8
// 365.022 us; speedup vs baseline: 4.6089x; 1.0222x over previous
//
#include <hip/hip_runtime.h>

// ConvLSTM2D via MFMA implicit-GEMM. B=8,T=16,H=W=64,Cin=32,F=64,3x3 SAME.
// Round 15: R14 skeleton (group-of-3 K-loop + async h-issue + c-prefetch,
// 373us) + two locality/latency edits:
//  (1) XCD-aware work mapping: 1D grid, batch = bid & 7. Flat block IDs
//      round-robin across the 8 XCDs, so all 32 blocks of one batch land
//      on one XCD; the per-batch working set (h ping+pong 1MB + c 1MB +
//      x-slice 0.5MB + weights 0.4MB ~= 3MB) fits its 4MB L2. h-halo and
//      c reads (written by the SAME XCD last launch) become ~200cy L2
//      hits instead of ~900cy cross-XCD/HBM accesses.
//  (2) split publication: K-groups 0-6 read only xs_s, so the h reg->LDS
//      writes move from the pre-K serial path to just before group 6's
//      closing barrier (first h read is group 9). h global loads get
//      x-stage + 3 k-groups (~4000cy) to land; pre-K serial phase = x-stage
//      only.
// Context: R7-R12 five K-loop schedules 428-464us (latency-bound, nothing
// saturated; R13's counters: MfmaUtil 5.6%, VALUBusy 2.7%); R13 persistent
// grid.sync = 1682us (device fences kill L2 reuse); R14 async-split = 373us
// (WIN, matched prediction). This round continues the latency-chain attack.

#define TSTEPS 16

typedef short bf16x8 __attribute__((ext_vector_type(8)));
typedef float f32x4 __attribute__((ext_vector_type(4)));
typedef unsigned int __attribute__((address_space(1))) gu32;
typedef unsigned int __attribute__((address_space(3))) lu32;

__device__ __forceinline__ float hsig(float x) {
    return fminf(fmaxf((x + 3.0f) * (1.0f / 6.0f), 0.0f), 1.0f);
}

__device__ __forceinline__ unsigned short f2bf(float f) {
    union { float f; unsigned int u; } v; v.f = f;
    unsigned int r = v.u + 0x7fffu + ((v.u >> 16) & 1u);  // RNE
    return (unsigned short)(r >> 16);
}

// ---- weight prepack: Wg(3,3,32,256), Ug(3,3,64,256) fp32 -> bf16 B-frags ----
// layout out[s(27)][nt(16)][lane(64)][8]: per (s,nt) one contiguous 1 KB line.
__global__ __launch_bounds__(256)
void prepack_w(const float* __restrict__ Wg, const float* __restrict__ Ug,
               unsigned short* __restrict__ out)
{
    int idx = blockIdx.x * 256 + threadIdx.x;   // 27*16*64 = 27648
    if (idx >= 27648) return;
    int lane = idx & 63;
    int nt   = (idx >> 6) & 15;
    int s    = idx >> 10;
    int col = lane & 15, quad = lane >> 4;
    int n = nt * 16 + col;
    int k0 = quad * 8;
    const float* src;
    if (s < 9) {
        src = Wg + ((size_t)s * 32 + k0) * 256 + n;
    } else {
        int ss = s - 9; int tap = ss >> 1; int half = ss & 1;
        src = Ug + ((size_t)tap * 64 + half * 32 + k0) * 256 + n;
    }
    unsigned short tmp[8];
    #pragma unroll
    for (int j = 0; j < 8; ++j) tmp[j] = f2bf(src[(size_t)j * 256]);
    *(uint4*)(out + (size_t)idx * 8) = *(uint4*)tmp;
}

// ---- one ConvLSTM step (NS = 9 for t==0, 27 otherwise) ----
template<int NS>
__global__ __launch_bounds__(512)
__attribute__((amdgpu_waves_per_eu(2, 2)))
void convlstm_step(const float* __restrict__ x,       // (B,T,64,64,32) fp32
                   const unsigned short* __restrict__ wpk,
                   const float* __restrict__ bias,    // (256)
                   const unsigned short* __restrict__ h_in, // bf16 (B,64,64,64)
                   float* __restrict__ c_st,          // fp32 (B,64,64,64) = d_out
                   unsigned short* __restrict__ h_out,// bf16 ping
                   int t, int is_last)
{
    constexpr bool HP = (NS == 27);
    constexpr int  P  = 6;   // B ring depth (2 groups of 3 k-steps)

    // tile: 16 rows (y) x 8 cols (x) = 128 px; halo 18x10 = 180 px
    __shared__ __align__(16) unsigned short xs_s[180 * 40];           // 14.4 KB
    __shared__ __align__(16) unsigned short hs_s[HP ? 180 * 72 : 8];  // 25.9 KB
    __shared__ __align__(16) unsigned short bring[P * 16 * 512];      // 96.0 KB

    const int tid = threadIdx.x;
    // (1) XCD-aware decode: batch = bid&7 (bid%8 ~ XCD round-robin), so one
    // batch's 32 tiles co-reside on one XCD and its h/c/x set is L2-local.
    const int bid  = blockIdx.x;
    const int b    = bid & 7;
    const int tile = bid >> 3;             // 0..31
    const int gx0  = (tile & 7) * 8;
    const int gy0  = (tile >> 3) * 16;

    const int lane  = tid & 63;
    const int w     = tid >> 6;        // wave 0..7
    const int pxgrp = w >> 2;          // 0: rows 0-7, 1: rows 8-15
    const int ngrp  = w & 3;           // n-group: nt in {ngrp, ngrp+4, ngrp+8, ngrp+12}
    const int quad  = lane >> 4;
    const int m     = lane & 15;
    const int ch    = ngrp * 16 + m;   // output channel 0..63

    // ---- B DMA: wave w stages nt {w, w+8} for k-step s into slot s%P ----
    auto issueDMA = [&](int s) {
        int slot = s % P;
        #pragma unroll
        for (int g = 0; g < 2; ++g) {
            int nt = w + 8 * g;
            const unsigned short* gp = wpk + ((size_t)(s * 16 + nt) * 64 + lane) * 8;
            unsigned short* lp = bring + ((size_t)slot * 16 + nt) * 512;  // uniform
            __builtin_amdgcn_global_load_lds((const gu32*)gp, (lu32*)lp, 16, 0, 0);
        }
    };

    // ---- prologue: fill group-0 slots; staging barrier certifies them ----
    issueDMA(0);
    issueDMA(1);
    issueDMA(2);

    // ---- h halo: ISSUE loads into regs first; latency hides under the
    // x-stage AND K-groups 0-6 (hs_s not read until group 9). 1440 items /
    // 512 thr = 3 rounds (3rd partial: tid < 416).
    uint4 hv0 = make_uint4(0u,0u,0u,0u), hv1 = make_uint4(0u,0u,0u,0u),
          hv2 = make_uint4(0u,0u,0u,0u);
    int ho0 = 0, ho1 = 0, ho2 = -1;
    if constexpr (HP) {
        const unsigned short* hb = h_in + ((size_t)b * (64 * 64 * 64));
        auto issueH = [&](int idx, uint4& v, int& off) {
            int pix = idx >> 3, q = idx & 7;
            int iy = pix / 10, ix = pix - iy * 10;
            int gy = gy0 + iy - 1, gx = gx0 + ix - 1;
            if ((unsigned)gy < 64u && (unsigned)gx < 64u)
                v = *(const uint4*)(hb + ((size_t)(gy * 64 + gx) * 64) + q * 8);
            off = pix * 72 + q * 8;
        };
        issueH(tid,        hv0, ho0);
        issueH(tid + 512,  hv1, ho1);
        if (tid < 416) issueH(tid + 1024, hv2, ho2);
    }

    // ---- stage x halo (fp32 -> bf16); h loads in flight meanwhile ----
    {
        const float* xt = x + (((size_t)b * TSTEPS + t) * (size_t)(64 * 64 * 32));
        #pragma unroll 3
        for (int idx = tid; idx < 180 * 8; idx += 512) {
            int pix = idx >> 3, q = idx & 7;
            int iy = pix / 10, ix = pix - iy * 10;
            int gy = gy0 + iy - 1, gx = gx0 + ix - 1;
            unsigned short o[4] = {0, 0, 0, 0};
            if ((unsigned)gy < 64u && (unsigned)gx < 64u) {
                float4 v = *(const float4*)(xt + ((size_t)(gy * 64 + gx) * 32) + q * 4);
                o[0] = f2bf(v.x); o[1] = f2bf(v.y); o[2] = f2bf(v.z); o[3] = f2bf(v.w);
            }
            *(ushort4*)(xs_s + pix * 40 + q * 4) = *(ushort4*)o;
        }
    }
    __syncthreads();   // xs_s + ring slots 0-2 visible (h still in regs)

    int xb[4], hb_[4];
    #pragma unroll
    for (int mt = 0; mt < 4; ++mt) {
        int p = mt * 16 + m;
        int row = pxgrp * 8 + (p >> 3);
        int cc  = p & 7;
        xb[mt]  = (row * 10 + cc) * 40 + quad * 8;
        hb_[mt] = (row * 10 + cc) * 72 + quad * 8;
    }

    // acc init = bias
    f32x4 acc[4][4];   // [mt][gate]
    #pragma unroll
    for (int g = 0; g < 4; ++g) {
        float bv = bias[g * 64 + ch];
        f32x4 bi = (f32x4){bv, bv, bv, bv};
        #pragma unroll
        for (int mt = 0; mt < 4; ++mt) acc[mt][g] = bi;
    }

    // c prefetch target; for NS=9 it's just zeros.
    float cpre[4][4];
    if constexpr (!HP) {
        #pragma unroll
        for (int mt = 0; mt < 4; ++mt)
            #pragma unroll
            for (int r = 0; r < 4; ++r) cpre[mt][r] = 0.0f;
    }

    // ---- K-loop: 3 k-steps per barrier, free scheduling within a group ----
    #pragma unroll
    for (int g0 = 0; g0 < NS; g0 += 3) {
        // stage next group's slots (other ring half; consumed-and-published
        // two barriers ago, so overwrite is safe)
        if (g0 + 3 < NS) { issueDMA(g0 + 3); issueDMA(g0 + 4); issueDMA(g0 + 5); }

        // issue the c_st prefetch at group 18: ~8K cyc before the epilogue
        // consumes it; later group barriers' vmcnt drains absorb completion.
        if constexpr (HP) {
            if (g0 == 18) {
                #pragma unroll
                for (int mt = 0; mt < 4; ++mt)
                    #pragma unroll
                    for (int r = 0; r < 4; ++r) {
                        int p = mt * 16 + quad * 4 + r;
                        int py = pxgrp * 8 + (p >> 3), px = p & 7;
                        size_t gidx = (((size_t)b * 64 + (gy0 + py)) * 64 + (gx0 + px)) * 64 + ch;
                        cpre[mt][r] = c_st[gidx];
                    }
            }
        }

        #pragma unroll
        for (int j = 0; j < 3; ++j) {
            const int s = g0 + j;           // compile-time
            const int slot = s % P;

            bf16x8 bfr[4];
            #pragma unroll
            for (int g = 0; g < 4; ++g)
                bfr[g] = *(const bf16x8*)(bring + ((size_t)slot * 16 + (ngrp + 4 * g)) * 512 + lane * 8);

            bf16x8 a[4];
            if (s < 9) {
                int taplin = (s / 3) * 10 + (s % 3);
                #pragma unroll
                for (int mt = 0; mt < 4; ++mt)
                    a[mt] = *(const bf16x8*)(xs_s + xb[mt] + taplin * 40);
            } else {
                int ss = s - 9, tap = ss >> 1, half = ss & 1;
                int taplin = (tap / 3) * 10 + (tap % 3);
                #pragma unroll
                for (int mt = 0; mt < 4; ++mt)
                    a[mt] = *(const bf16x8*)(hs_s + hb_[mt] + taplin * 72 + half * 32);
            }

            #pragma unroll
            for (int g = 0; g < 4; ++g)
                #pragma unroll
                for (int mt = 0; mt < 4; ++mt)
                    acc[mt][g] = __builtin_amdgcn_mfma_f32_16x16x32_bf16(a[mt], bfr[g], acc[mt][g], 0, 0, 0);
        }

        // (2) write h halo to LDS just before group 6's closing barrier:
        // first hs_s read is group 9, so THIS barrier publishes it. The h
        // global loads had x-stage + groups 0-6 to land.
        if constexpr (HP) {
            if (g0 == 6) {
                *(uint4*)(hs_s + ho0) = hv0;
                *(uint4*)(hs_s + ho1) = hv1;
                if (ho2 >= 0) *(uint4*)(hs_s + ho2) = hv2;
            }
        }

        // group boundary: drains the in-flight DMAs (vmcnt(0)) and
        // publishes next group's slots (and hs_s at g0==6) to all waves
        __syncthreads();
    }

    // ---- epilogue: gates + state update (c from registers) ----
    // C/D layout: col = lane&15 (channel), row = quad*4 + r (pixel)
    #pragma unroll
    for (int mt = 0; mt < 4; ++mt) {
        #pragma unroll
        for (int r = 0; r < 4; ++r) {
            int p = mt * 16 + quad * 4 + r;
            int py = pxgrp * 8 + (p >> 3), px = p & 7;
            size_t gidx = (((size_t)b * 64 + (gy0 + py)) * 64 + (gx0 + px)) * 64 + ch;
            float zi = acc[mt][0][r];
            float zf = acc[mt][1][r];
            float zc = acc[mt][2][r];
            float zo = acc[mt][3][r];
            float cn = hsig(zf) * cpre[mt][r] + hsig(zi) * fmaxf(zc, 0.0f);
            float hn = hsig(zo) * fmaxf(cn, 0.0f);
            if (is_last) {
                c_st[gidx] = hn;            // d_out gets final h (fp32)
            } else {
                c_st[gidx] = cn;
                h_out[gidx] = f2bf(hn);
            }
        }
    }
}

extern "C" void kernel_launch(void* const* d_in, const int* in_sizes, int n_in,
                              void* d_out, int out_size, void* d_ws, size_t ws_size,
                              hipStream_t stream) {
    const float* x  = (const float*)d_in[0];
    const float* Wg = (const float*)d_in[1];
    const float* Ug = (const float*)d_in[2];
    const float* bs = (const float*)d_in[3];

    // ws layout: [packed weights 442368 B][h0 bf16 4 MB][h1 bf16 4 MB]
    unsigned short* wpk = (unsigned short*)d_ws;
    unsigned short* h0  = (unsigned short*)((char*)d_ws + 27 * 16 * 64 * 8 * 2);
    unsigned short* h1  = h0 + (size_t)8 * 64 * 64 * 64;
    float* cS = (float*)d_out;

    prepack_w<<<108, 256, 0, stream>>>(Wg, Ug, wpk);

    dim3 grid(256);   // 1D; decode: b = bid&7 (XCD), tile = bid>>3
    dim3 block(512);
    for (int t = 0; t < TSTEPS; ++t) {
        const unsigned short* hin = (t == 0) ? h0 : ((t & 1) ? h0 : h1);
        unsigned short* hout = (t & 1) ? h1 : h0;
        if (t == 0) {
            convlstm_step<9><<<grid, block, 0, stream>>>(x, wpk, bs, hin, cS, hout, t, 0);
        } else {
            convlstm_step<27><<<grid, block, 0, stream>>>(x, wpk, bs, hin, cS, hout,
                                                          t, (t == TSTEPS - 1) ? 1 : 0);
        }
    }
}